// Round 4
// baseline (14383.051 us; speedup 1.0000x reference)
//
#include <hip/hip_runtime.h>
#include <hip/hip_bf16.h>

#define NPROJ 160

// One self-contained persistent kernel: 256 blocks x 512 threads, 4 batch rows
// per block, 64 sequential decode steps. No workspace usage at all.
// Output dtype: float32 (reference returns fp32).
__global__ __launch_bounds__(512) void k_all(
    const float* __restrict__ tc, const float* __restrict__ cc,
    const float* __restrict__ initv,
    const float* __restrict__ W_cf, const float* __restrict__ b_cf,
    const float* __restrict__ ln_g, const float* __restrict__ ln_b,
    const float* __restrict__ W_feat, const float* __restrict__ b_feat,
    const float* __restrict__ W_inproj, const float* __restrict__ b_inproj,
    const float* __restrict__ conv_w, const float* __restrict__ conv_b,
    const float* __restrict__ Wxp,
    const float* __restrict__ Wdt, const float* __restrict__ b_dt,
    const float* __restrict__ D_param,
    const float* __restrict__ Wout, const float* __restrict__ b_out,
    const float* __restrict__ Wtr, const float* __restrict__ b_tr,
    const float* __restrict__ Wse, const float* __restrict__ b_se,
    const float* __restrict__ W_fin, const float* __restrict__ b_fin,
    float* __restrict__ out) {
  __shared__ float x2[4][1024];    // [tc|cc] staging (prologue only)
  __shared__ float hb[4][512];     // h -> fused (in place)
  __shared__ float hin[4][512];
  __shared__ float wf7[7][512];    // W_feat rows 512..518
  __shared__ float xc[4][1024];    // x_c, later y (in place)
  __shared__ float zs[4][1024];    // silu(z)
  __shared__ float proj[4][NPROJ];
  __shared__ float mrow[4][512];
  __shared__ float combs[4][8];
  __shared__ float bcv[4];
  __shared__ float ts[4][16];
  __shared__ float part[8][4][16];

  const int t = threadIdx.x;       // 0..511
  const int r0 = blockIdx.x * 4;

  // ---------- prologue: stage inputs ----------
  for (int idx = t; idx < 4096; idx += 512) {
    int r = idx >> 10, k = idx & 1023;
    x2[r][k] = (k < 512) ? tc[(size_t)(r0 + r) * 512 + k]
                         : cc[(size_t)(r0 + r) * 512 + (k - 512)];
  }
  for (int idx = t; idx < 3584; idx += 512) {
    int i = idx >> 9, k = idx & 511;
    wf7[i][k] = W_feat[(size_t)(512 + i) * 512 + k];
  }
  __syncthreads();

  // ---------- h = relu([tc,cc] @ W_cf + b_cf) ----------
  {
    int o = t;
    float a0 = 0, a1 = 0, a2 = 0, a3 = 0;
    for (int k = 0; k < 1024; ++k) {
      float w = W_cf[(size_t)k * 512 + o];
      a0 += x2[0][k] * w; a1 += x2[1][k] * w; a2 += x2[2][k] * w; a3 += x2[3][k] * w;
    }
    float b = b_cf[o];
    hb[0][o] = fmaxf(a0 + b, 0.f); hb[1][o] = fmaxf(a1 + b, 0.f);
    hb[2][o] = fmaxf(a2 + b, 0.f); hb[3][o] = fmaxf(a3 + b, 0.f);
  }
  __syncthreads();

  // ---------- LayerNorm -> fused (in place in hb), waves 0..3 ----------
  if (t < 256) {
    int w = t >> 6, lane = t & 63;
    float s = 0.f, s2 = 0.f;
    for (int j = lane; j < 512; j += 64) { float v = hb[w][j]; s += v; s2 += v * v; }
#pragma unroll
    for (int off = 32; off; off >>= 1) { s += __shfl_xor(s, off); s2 += __shfl_xor(s2, off); }
    float mu = s * (1.f / 512.f);
    float var = s2 * (1.f / 512.f) - mu * mu;
    float inv = rsqrtf(var + 1e-5f);
    for (int j = lane; j < 512; j += 64)
      hb[w][j] = (hb[w][j] - mu) * inv * ln_g[j] + ln_b[j];
  }
  __syncthreads();

  // ---------- hin = fused @ W_feat[:512] + b_feat ----------
  {
    int o = t;
    float a0 = 0, a1 = 0, a2 = 0, a3 = 0;
    for (int k = 0; k < 512; ++k) {
      float w = W_feat[(size_t)k * 512 + o];
      a0 += hb[0][k] * w; a1 += hb[1][k] * w; a2 += hb[2][k] * w; a3 += hb[3][k] * w;
    }
    float b = b_feat[o];
    hin[0][o] = a0 + b; hin[1][o] = a1 + b; hin[2][o] = a2 + b; hin[3][o] = a3 + b;
  }
  __syncthreads();

  // ---------- xz_base (into registers) + rank-7 fold Wcx (into registers) ----
  float xzbx[4][2], xzbz[4][2];
  float wcxx[7][2], wcxz[7][2];
#pragma unroll
  for (int jj = 0; jj < 2; ++jj) {
#pragma unroll
    for (int half = 0; half < 2; ++half) {
      int col = t + jj * 512 + half * 1024;
      float a0 = 0, a1 = 0, a2 = 0, a3 = 0;
      float w0 = 0, w1 = 0, w2 = 0, w3 = 0, w4 = 0, w5 = 0, w6 = 0;
      for (int k = 0; k < 512; ++k) {
        float wi = W_inproj[(size_t)k * 2048 + col];
        a0 += hin[0][k] * wi; a1 += hin[1][k] * wi;
        a2 += hin[2][k] * wi; a3 += hin[3][k] * wi;
        w0 += wf7[0][k] * wi; w1 += wf7[1][k] * wi; w2 += wf7[2][k] * wi;
        w3 += wf7[3][k] * wi; w4 += wf7[4][k] * wi; w5 += wf7[5][k] * wi;
        w6 += wf7[6][k] * wi;
      }
      float bi = b_inproj[col];
      if (half == 0) {
        xzbx[0][jj] = a0 + bi; xzbx[1][jj] = a1 + bi;
        xzbx[2][jj] = a2 + bi; xzbx[3][jj] = a3 + bi;
        wcxx[0][jj] = w0; wcxx[1][jj] = w1; wcxx[2][jj] = w2; wcxx[3][jj] = w3;
        wcxx[4][jj] = w4; wcxx[5][jj] = w5; wcxx[6][jj] = w6;
      } else {
        xzbz[0][jj] = a0 + bi; xzbz[1][jj] = a1 + bi;
        xzbz[2][jj] = a2 + bi; xzbz[3][jj] = a3 + bi;
        wcxz[0][jj] = w0; wcxz[1][jj] = w1; wcxz[2][jj] = w2; wcxz[3][jj] = w3;
        wcxz[4][jj] = w4; wcxz[5][jj] = w5; wcxz[6][jj] = w6;
      }
    }
  }

  // ---------- step-invariant per-thread constants ----------
  float cw3[2], cbv[2], dpar[2], bdtv[2];
#pragma unroll
  for (int jj = 0; jj < 2; ++jj) {
    int j = t + jj * 512;
    cw3[jj] = conv_w[j * 4 + 3];
    cbv[jj] = conv_b[j];
    dpar[jj] = D_param[j];
    bdtv[jj] = b_dt[j];
  }
  const float boutr = b_out[t];

  if (t < 28) combs[t / 7][t % 7] = initv[(r0 + t / 7) * 7 + (t % 7)];
  __syncthreads();

  // ---------- 64 sequential decode steps ----------
  for (int step = 0; step < 64; ++step) {
    // P1: xz = xz_base + comb @ Wcx; x_c = silu(x*cw3+cb); zs = silu(z)
#pragma unroll
    for (int r = 0; r < 4; ++r) {
#pragma unroll
      for (int jj = 0; jj < 2; ++jj) {
        int j = t + jj * 512;
        float v = xzbx[r][jj];
        float u = xzbz[r][jj];
#pragma unroll
        for (int i = 0; i < 7; ++i) {
          float cb_ = combs[r][i];
          v += cb_ * wcxx[i][jj];
          u += cb_ * wcxz[i][jj];
        }
        v = v * cw3[jj] + cbv[jj];
        xc[r][j] = v / (1.f + expf(-v));
        zs[r][j] = u / (1.f + expf(-u));
      }
    }
    __syncthreads();
    // P2: proj = x_c @ W_xproj  (160 outputs per row)
    if (t < 480) {
      int r = t / NPROJ;
      int p = t - r * NPROJ;
      const float2* xr = reinterpret_cast<const float2*>(&xc[r][0]);
      const float2* x3 = reinterpret_cast<const float2*>(&xc[3][0]);
      float a = 0.f, a3 = 0.f;
#pragma unroll 4
      for (int k2 = 0; k2 < 512; ++k2) {
        float w0 = Wxp[(size_t)(2 * k2) * NPROJ + p];
        float w1 = Wxp[(size_t)(2 * k2 + 1) * NPROJ + p];
        float2 xv = xr[k2];
        a += xv.x * w0 + xv.y * w1;
        if (r == 0) { float2 x3v = x3[k2]; a3 += x3v.x * w0 + x3v.y * w1; }
      }
      proj[r][p] = a;
      if (r == 0) proj[3][p] = a3;
    }
    __syncthreads();
    // bc = <Bm, Cm> per row
    if (t < 256) {
      int r = t >> 6, n = t & 63;
      float pr = proj[r][32 + n] * proj[r][96 + n];
#pragma unroll
      for (int off = 32; off; off >>= 1) pr += __shfl_xor(pr, off);
      if (n == 0) bcv[r] = pr;
    }
    __syncthreads();
    // P3: dt = softplus(dt_r @ W_dt + b_dt); y = (dt*bc + D)*x_c*zs -> xc
#pragma unroll
    for (int jj = 0; jj < 2; ++jj) {
      int j = t + jj * 512;
      float a0 = bdtv[jj], a1 = bdtv[jj], a2 = bdtv[jj], a3 = bdtv[jj];
#pragma unroll
      for (int q2 = 0; q2 < 16; ++q2) {
        float w0 = Wdt[(size_t)(2 * q2) * 1024 + j];
        float w1 = Wdt[(size_t)(2 * q2 + 1) * 1024 + j];
        float2 p0 = reinterpret_cast<const float2*>(&proj[0][0])[q2];
        float2 p1 = reinterpret_cast<const float2*>(&proj[1][0])[q2];
        float2 p2 = reinterpret_cast<const float2*>(&proj[2][0])[q2];
        float2 p3 = reinterpret_cast<const float2*>(&proj[3][0])[q2];
        a0 += p0.x * w0 + p0.y * w1;
        a1 += p1.x * w0 + p1.y * w1;
        a2 += p2.x * w0 + p2.y * w1;
        a3 += p3.x * w0 + p3.y * w1;
      }
      float accs[4] = {a0, a1, a2, a3};
#pragma unroll
      for (int r = 0; r < 4; ++r) {
        float v = accs[r];
        float sp = fmaxf(v, 0.f) + log1pf(expf(-fabsf(v)));
        float y = (sp * bcv[r] + dpar[jj]) * xc[r][j] * zs[r][j];
        xc[r][j] = y;
      }
    }
    __syncthreads();
    // P4: m = y @ W_out + b_out
    {
      int o = t;
      const float2* y0 = reinterpret_cast<const float2*>(&xc[0][0]);
      const float2* y1 = reinterpret_cast<const float2*>(&xc[1][0]);
      const float2* y2 = reinterpret_cast<const float2*>(&xc[2][0]);
      const float2* y3 = reinterpret_cast<const float2*>(&xc[3][0]);
      float a0 = 0, a1 = 0, a2 = 0, a3 = 0;
#pragma unroll 4
      for (int k2 = 0; k2 < 512; ++k2) {
        float w0 = Wout[(size_t)(2 * k2) * 512 + o];
        float w1 = Wout[(size_t)(2 * k2 + 1) * 512 + o];
        float2 v0 = y0[k2], v1 = y1[k2], v2 = y2[k2], v3 = y3[k2];
        a0 += v0.x * w0 + v0.y * w1;
        a1 += v1.x * w0 + v1.y * w1;
        a2 += v2.x * w0 + v2.y * w1;
        a3 += v3.x * w0 + v3.y * w1;
      }
      mrow[0][o] = a0 + boutr; mrow[1][o] = a1 + boutr;
      mrow[2][o] = a2 + boutr; mrow[3][o] = a3 + boutr;
    }
    __syncthreads();
    // P5: trend/seas partials
    if (t < 448) {
      int chunk = t / 56, u = t - chunk * 56;
      int r = u / 14, c = u - r * 14;
      const float* W = (c < 7) ? Wtr : Wse;
      int cc_ = (c < 7) ? c : c - 7;
      float s = 0.f;
      int o0 = chunk * 64;
#pragma unroll 8
      for (int o = o0; o < o0 + 64; ++o) s += mrow[r][o] * W[o * 7 + cc_];
      part[chunk][r][c] = s;
    }
    __syncthreads();
    if (t < 56) {
      int r = t / 14, c = t - (t / 14) * 14;
      float s = (c < 7) ? b_tr[c] : b_se[c - 7];
#pragma unroll
      for (int ch = 0; ch < 8; ++ch) s += part[ch][r][c];
      ts[r][c] = s;
      size_t idx = ((size_t)(r0 + r) * 64 + step) * 7;
      if (c < 7) out[idx + c] = s;
      else out[458752 + idx + (c - 7)] = s;
    }
    __syncthreads();
    if (t < 28) {
      int r = t / 7, c = t - (t / 7) * 7;
      float s = b_fin[c];
#pragma unroll
      for (int i = 0; i < 14; ++i) s += ts[r][i] * W_fin[i * 7 + c];
      combs[r][c] = s;
      out[917504 + ((size_t)(r0 + r) * 64 + step) * 7 + c] = s;
    }
    __syncthreads();
  }
}

extern "C" void kernel_launch(void* const* d_in, const int* in_sizes, int n_in,
                              void* d_out, int out_size, void* d_ws, size_t ws_size,
                              hipStream_t stream) {
  const float* tc       = (const float*)d_in[0];
  const float* cc       = (const float*)d_in[1];
  const float* initv    = (const float*)d_in[2];
  const float* W_cf     = (const float*)d_in[3];
  const float* b_cf     = (const float*)d_in[4];
  const float* ln_g     = (const float*)d_in[5];
  const float* ln_b     = (const float*)d_in[6];
  const float* W_feat   = (const float*)d_in[7];
  const float* b_feat   = (const float*)d_in[8];
  const float* W_inproj = (const float*)d_in[9];
  const float* b_inproj = (const float*)d_in[10];
  const float* conv_w   = (const float*)d_in[11];
  const float* conv_b   = (const float*)d_in[12];
  const float* W_xproj  = (const float*)d_in[13];
  const float* W_dt     = (const float*)d_in[14];
  const float* b_dt     = (const float*)d_in[15];
  const float* D_param  = (const float*)d_in[16];
  const float* W_out    = (const float*)d_in[17];
  const float* b_out    = (const float*)d_in[18];
  const float* W_tr     = (const float*)d_in[19];
  const float* b_tr     = (const float*)d_in[20];
  const float* W_se     = (const float*)d_in[21];
  const float* b_se     = (const float*)d_in[22];
  const float* W_fin    = (const float*)d_in[23];
  const float* b_fin    = (const float*)d_in[24];

  hipLaunchKernelGGL(k_all, dim3(256), dim3(512), 0, stream,
                     tc, cc, initv, W_cf, b_cf, ln_g, ln_b, W_feat, b_feat,
                     W_inproj, b_inproj, conv_w, conv_b, W_xproj, W_dt, b_dt,
                     D_param, W_out, b_out, W_tr, b_tr, W_se, b_se, W_fin, b_fin,
                     (float*)d_out);
}

// Round 5
// 4837.234 us; speedup vs baseline: 2.9734x; 2.9734x over previous
//
#include <hip/hip_runtime.h>
#include <hip/hip_bf16.h>

// Persistent fused decoder: 256 blocks x 1024 threads, 4 batch rows/block,
// 64 sequential steps. fp32 throughout (absmax margin 8x). Key structure:
//  - rank-7 feedback folding: per-step inproj collapses to comb @ Wcx (7x2048)
//  - K-split GEMV phases with LDS partial reduction -> ~halved per-thread work
//  - 16 waves/CU (vs 8 in round-4 kernel): latency hiding was the bottleneck
//    (VALUBusy 18.6%, Occupancy 24%, 5x latency-stall vs issue stream)

struct Pro {                      // prologue-only arrays
  float x2[4][1024];              // [tc|cc]
  float hb[4][512];               // h -> fused (in place)
  float hin[4][512];
  float wf7[7][512];              // W_feat rows 512..518
  float hpart[2][4][512];         // K-split partials
};
struct Sc {                       // scan-phase arrays
  float xc[4][1024];              // x_c, later y (in place)
  float proj[4][160];             // only [:, :32] (dt_r) reduced here
  float part4[2][4][512];         // P4 K-split partials
  float part2[4][4][160];         // P2 K-split partials
  float part5[16][4][14];         // P5 chunk partials
  float combs[4][8];
  float bcv[4];
  float ts[4][16];
  float bo[512];                  // b_out staged
};
union SMem { Pro pro; Sc sc; };

__global__ __launch_bounds__(1024) void k_all(
    const float* __restrict__ tc, const float* __restrict__ cc,
    const float* __restrict__ initv,
    const float* __restrict__ W_cf, const float* __restrict__ b_cf,
    const float* __restrict__ ln_g, const float* __restrict__ ln_b,
    const float* __restrict__ W_feat, const float* __restrict__ b_feat,
    const float* __restrict__ W_inproj, const float* __restrict__ b_inproj,
    const float* __restrict__ conv_w, const float* __restrict__ conv_b,
    const float* __restrict__ Wxp,
    const float* __restrict__ Wdt, const float* __restrict__ b_dt,
    const float* __restrict__ D_param,
    const float* __restrict__ Wout, const float* __restrict__ b_out,
    const float* __restrict__ Wtr, const float* __restrict__ b_tr,
    const float* __restrict__ Wse, const float* __restrict__ b_se,
    const float* __restrict__ W_fin, const float* __restrict__ b_fin,
    float* __restrict__ out) {
  __shared__ SMem S;
  const int t = threadIdx.x;            // 0..1023
  const int r0 = blockIdx.x * 4;
  const int o9 = t & 511;               // output index for 512-wide phases
  const int kc9 = t >> 9;               // K-split half index

  // ================= prologue =================
  for (int idx = t; idx < 4096; idx += 1024) {
    int r = idx >> 10, k = idx & 1023;
    S.pro.x2[r][k] = (k < 512) ? tc[(size_t)(r0 + r) * 512 + k]
                               : cc[(size_t)(r0 + r) * 512 + (k - 512)];
  }
  for (int idx = t; idx < 3584; idx += 1024) {
    int i = idx >> 9, k = idx & 511;
    S.pro.wf7[i][k] = W_feat[(size_t)(512 + i) * 512 + k];
  }
  __syncthreads();

  // h = relu([tc,cc] @ W_cf + b_cf), K=1024 split in 2 halves
  {
    float a0 = 0, a1 = 0, a2 = 0, a3 = 0;
    int k0 = kc9 * 512;
    for (int k = k0; k < k0 + 512; ++k) {
      float w = W_cf[(size_t)k * 512 + o9];
      a0 += S.pro.x2[0][k] * w; a1 += S.pro.x2[1][k] * w;
      a2 += S.pro.x2[2][k] * w; a3 += S.pro.x2[3][k] * w;
    }
    S.pro.hpart[kc9][0][o9] = a0; S.pro.hpart[kc9][1][o9] = a1;
    S.pro.hpart[kc9][2][o9] = a2; S.pro.hpart[kc9][3][o9] = a3;
  }
  __syncthreads();
  {
    int rh = kc9;  // handles rows 2rh, 2rh+1
    float b = b_cf[o9];
#pragma unroll
    for (int rr = 0; rr < 2; ++rr) {
      int r = rh * 2 + rr;
      S.pro.hb[r][o9] = fmaxf(S.pro.hpart[0][r][o9] + S.pro.hpart[1][r][o9] + b, 0.f);
    }
  }
  __syncthreads();
  // LayerNorm -> fused (in place)
  if (t < 256) {
    int w = t >> 6, lane = t & 63;
    float s = 0.f, s2 = 0.f;
    for (int j = lane; j < 512; j += 64) { float v = S.pro.hb[w][j]; s += v; s2 += v * v; }
#pragma unroll
    for (int off = 32; off; off >>= 1) { s += __shfl_xor(s, off); s2 += __shfl_xor(s2, off); }
    float mu = s * (1.f / 512.f);
    float var = s2 * (1.f / 512.f) - mu * mu;
    float inv = rsqrtf(var + 1e-5f);
    for (int j = lane; j < 512; j += 64)
      S.pro.hb[w][j] = (S.pro.hb[w][j] - mu) * inv * ln_g[j] + ln_b[j];
  }
  __syncthreads();
  // hin = fused @ W_feat[:512] + b_feat, K=512 split in 2
  {
    float a0 = 0, a1 = 0, a2 = 0, a3 = 0;
    int k0 = kc9 * 256;
    for (int k = k0; k < k0 + 256; ++k) {
      float w = W_feat[(size_t)k * 512 + o9];
      a0 += S.pro.hb[0][k] * w; a1 += S.pro.hb[1][k] * w;
      a2 += S.pro.hb[2][k] * w; a3 += S.pro.hb[3][k] * w;
    }
    S.pro.hpart[kc9][0][o9] = a0; S.pro.hpart[kc9][1][o9] = a1;
    S.pro.hpart[kc9][2][o9] = a2; S.pro.hpart[kc9][3][o9] = a3;
  }
  __syncthreads();
  {
    float b = b_feat[o9];
#pragma unroll
    for (int rr = 0; rr < 2; ++rr) {
      int r = kc9 * 2 + rr;
      S.pro.hin[r][o9] = S.pro.hpart[0][r][o9] + S.pro.hpart[1][r][o9] + b;
    }
  }
  __syncthreads();

  // xz_base + rank-7 fold Wcx, into registers. Thread t: x-col t, z-col 1024+t.
  float xzbx[4], xzbz[4], wcxx[7], wcxz[7];
#pragma unroll
  for (int half = 0; half < 2; ++half) {
    int col = t + half * 1024;
    float a0 = 0, a1 = 0, a2 = 0, a3 = 0;
    float w0 = 0, w1 = 0, w2 = 0, w3 = 0, w4 = 0, w5 = 0, w6 = 0;
    for (int k = 0; k < 512; ++k) {
      float wi = W_inproj[(size_t)k * 2048 + col];
      a0 += S.pro.hin[0][k] * wi; a1 += S.pro.hin[1][k] * wi;
      a2 += S.pro.hin[2][k] * wi; a3 += S.pro.hin[3][k] * wi;
      w0 += S.pro.wf7[0][k] * wi; w1 += S.pro.wf7[1][k] * wi;
      w2 += S.pro.wf7[2][k] * wi; w3 += S.pro.wf7[3][k] * wi;
      w4 += S.pro.wf7[4][k] * wi; w5 += S.pro.wf7[5][k] * wi;
      w6 += S.pro.wf7[6][k] * wi;
    }
    float bi = b_inproj[col];
    if (half == 0) {
      xzbx[0] = a0 + bi; xzbx[1] = a1 + bi; xzbx[2] = a2 + bi; xzbx[3] = a3 + bi;
      wcxx[0] = w0; wcxx[1] = w1; wcxx[2] = w2; wcxx[3] = w3; wcxx[4] = w4;
      wcxx[5] = w5; wcxx[6] = w6;
    } else {
      xzbz[0] = a0 + bi; xzbz[1] = a1 + bi; xzbz[2] = a2 + bi; xzbz[3] = a3 + bi;
      wcxz[0] = w0; wcxz[1] = w1; wcxz[2] = w2; wcxz[3] = w3; wcxz[4] = w4;
      wcxz[5] = w5; wcxz[6] = w6;
    }
  }

  // step-invariant per-thread constants (j = t)
  const float cw3  = conv_w[t * 4 + 3];
  const float cbv  = conv_b[t];
  const float dpar = D_param[t];
  const float bdtv = b_dt[t];

  // pro arrays dead from here; stage sc pre-loop data (hits only hpart region)
  if (t < 512) S.sc.bo[t] = b_out[t];
  if (t < 28) S.sc.combs[t / 7][t % 7] = initv[(r0 + t / 7) * 7 + (t % 7)];
  __syncthreads();

  // ================= 64 sequential decode steps =================
  float zsr[4], xcr[4];
  for (int step = 0; step < 64; ++step) {
    // P1: xz = xz_base + comb @ Wcx; x_c = silu(x*cw3+cb) -> LDS+reg; silu(z) -> reg
#pragma unroll
    for (int r = 0; r < 4; ++r) {
      float v = xzbx[r], u = xzbz[r];
#pragma unroll
      for (int i = 0; i < 7; ++i) {
        float cb_ = S.sc.combs[r][i];
        v += cb_ * wcxx[i];
        u += cb_ * wcxz[i];
      }
      v = v * cw3 + cbv;
      float sv = v / (1.f + expf(-v));
      xcr[r] = sv;
      S.sc.xc[r][t] = sv;
      zsr[r] = u / (1.f + expf(-u));
    }
    __syncthreads();

    // P2: proj partials = x_c @ W_xproj, K=1024 split in 4 quarters (640 threads)
    if (t < 640) {
      int kc = t / 160, p = t - kc * 160;
      const float2* x0 = reinterpret_cast<const float2*>(&S.sc.xc[0][0]);
      const float2* x1 = reinterpret_cast<const float2*>(&S.sc.xc[1][0]);
      const float2* x2_ = reinterpret_cast<const float2*>(&S.sc.xc[2][0]);
      const float2* x3 = reinterpret_cast<const float2*>(&S.sc.xc[3][0]);
      float a0 = 0, a1 = 0, a2 = 0, a3 = 0;
      int k20 = kc * 128;
#pragma unroll 4
      for (int k2 = k20; k2 < k20 + 128; ++k2) {
        float w0 = Wxp[(size_t)(2 * k2) * 160 + p];
        float w1 = Wxp[(size_t)(2 * k2 + 1) * 160 + p];
        float2 v0 = x0[k2], v1 = x1[k2], v2 = x2_[k2], v3 = x3[k2];
        a0 += v0.x * w0 + v0.y * w1;
        a1 += v1.x * w0 + v1.y * w1;
        a2 += v2.x * w0 + v2.y * w1;
        a3 += v3.x * w0 + v3.y * w1;
      }
      S.sc.part2[kc][0][p] = a0; S.sc.part2[kc][1][p] = a1;
      S.sc.part2[kc][2][p] = a2; S.sc.part2[kc][3][p] = a3;
    }
    __syncthreads();

    // reduce dt_r (proj[:, :32]) + bc = <Bm,Cm> in parallel thread ranges
    if (t < 128) {
      int r = t >> 5, p = t & 31;
      S.sc.proj[r][p] = S.sc.part2[0][r][p] + S.sc.part2[1][r][p] +
                        S.sc.part2[2][r][p] + S.sc.part2[3][r][p];
    } else if (t >= 256 && t < 512) {
      int r = (t - 256) >> 6, n = t & 63;
      float bm = S.sc.part2[0][r][32 + n] + S.sc.part2[1][r][32 + n] +
                 S.sc.part2[2][r][32 + n] + S.sc.part2[3][r][32 + n];
      float cm = S.sc.part2[0][r][96 + n] + S.sc.part2[1][r][96 + n] +
                 S.sc.part2[2][r][96 + n] + S.sc.part2[3][r][96 + n];
      float pr = bm * cm;
#pragma unroll
      for (int off = 32; off; off >>= 1) pr += __shfl_xor(pr, off);
      if (n == 0) S.sc.bcv[r] = pr;
    }
    __syncthreads();

    // P3: dt = softplus(dt_r @ W_dt + b_dt); y = (dt*bc + D)*x_c*silu(z) -> xc
    {
      float a0 = bdtv, a1 = bdtv, a2 = bdtv, a3 = bdtv;
#pragma unroll
      for (int q2 = 0; q2 < 16; ++q2) {
        float w0 = Wdt[(size_t)(2 * q2) * 1024 + t];
        float w1 = Wdt[(size_t)(2 * q2 + 1) * 1024 + t];
        float2 p0 = reinterpret_cast<const float2*>(&S.sc.proj[0][0])[q2];
        float2 p1 = reinterpret_cast<const float2*>(&S.sc.proj[1][0])[q2];
        float2 p2 = reinterpret_cast<const float2*>(&S.sc.proj[2][0])[q2];
        float2 p3 = reinterpret_cast<const float2*>(&S.sc.proj[3][0])[q2];
        a0 += p0.x * w0 + p0.y * w1;
        a1 += p1.x * w0 + p1.y * w1;
        a2 += p2.x * w0 + p2.y * w1;
        a3 += p3.x * w0 + p3.y * w1;
      }
      float accs[4] = {a0, a1, a2, a3};
#pragma unroll
      for (int r = 0; r < 4; ++r) {
        float v = accs[r];
        float sp = fmaxf(v, 0.f) + log1pf(expf(-fabsf(v)));
        S.sc.xc[r][t] = (sp * S.sc.bcv[r] + dpar) * xcr[r] * zsr[r];
      }
    }
    __syncthreads();

    // P4: part4 = y @ W_out, K=1024 split in 2 halves (all 1024 threads)
    {
      const float2* y0 = reinterpret_cast<const float2*>(&S.sc.xc[0][0]);
      const float2* y1 = reinterpret_cast<const float2*>(&S.sc.xc[1][0]);
      const float2* y2 = reinterpret_cast<const float2*>(&S.sc.xc[2][0]);
      const float2* y3 = reinterpret_cast<const float2*>(&S.sc.xc[3][0]);
      float a0 = 0, a1 = 0, a2 = 0, a3 = 0;
      int k20 = kc9 * 256;
#pragma unroll 4
      for (int k2 = k20; k2 < k20 + 256; ++k2) {
        float w0 = Wout[(size_t)(2 * k2) * 512 + o9];
        float w1 = Wout[(size_t)(2 * k2 + 1) * 512 + o9];
        float2 v0 = y0[k2], v1 = y1[k2], v2 = y2[k2], v3 = y3[k2];
        a0 += v0.x * w0 + v0.y * w1;
        a1 += v1.x * w0 + v1.y * w1;
        a2 += v2.x * w0 + v2.y * w1;
        a3 += v3.x * w0 + v3.y * w1;
      }
      S.sc.part4[kc9][0][o9] = a0; S.sc.part4[kc9][1][o9] = a1;
      S.sc.part4[kc9][2][o9] = a2; S.sc.part4[kc9][3][o9] = a3;
    }
    __syncthreads();

    // P5: trend/seas partials directly from part4 (m = part4[0]+part4[1]+bo)
    if (t < 896) {
      int chunk = t / 56, u = t - chunk * 56;
      int r = u / 14, c = u - r * 14;
      const float* W = (c < 7) ? Wtr : Wse;
      int cc_ = (c < 7) ? c : c - 7;
      float s = 0.f;
      int oo0 = chunk * 32;
#pragma unroll 4
      for (int o = oo0; o < oo0 + 32; ++o) {
        float m = S.sc.part4[0][r][o] + S.sc.part4[1][r][o] + S.sc.bo[o];
        s += m * W[o * 7 + cc_];
      }
      S.sc.part5[chunk][r][c] = s;
    }
    __syncthreads();

    // P6: finalize trend/seas, write out
    if (t < 56) {
      int r = t / 14, c = t - (t / 14) * 14;
      float s = (c < 7) ? b_tr[c] : b_se[c - 7];
#pragma unroll
      for (int ch = 0; ch < 16; ++ch) s += S.sc.part5[ch][r][c];
      S.sc.ts[r][c] = s;
      size_t idx = ((size_t)(r0 + r) * 64 + step) * 7;
      if (c < 7) out[idx + c] = s;
      else out[458752 + idx + (c - 7)] = s;
    }
    __syncthreads();

    // P7: comb = [trend,seas] @ W_fin + b_fin, write out + feedback
    if (t < 28) {
      int r = t / 7, c = t - (t / 7) * 7;
      float s = b_fin[c];
#pragma unroll
      for (int i = 0; i < 14; ++i) s += S.sc.ts[r][i] * W_fin[i * 7 + c];
      S.sc.combs[r][c] = s;
      out[917504 + ((size_t)(r0 + r) * 64 + step) * 7 + c] = s;
    }
    __syncthreads();
  }
}

extern "C" void kernel_launch(void* const* d_in, const int* in_sizes, int n_in,
                              void* d_out, int out_size, void* d_ws, size_t ws_size,
                              hipStream_t stream) {
  const float* tc       = (const float*)d_in[0];
  const float* cc       = (const float*)d_in[1];
  const float* initv    = (const float*)d_in[2];
  const float* W_cf     = (const float*)d_in[3];
  const float* b_cf     = (const float*)d_in[4];
  const float* ln_g     = (const float*)d_in[5];
  const float* ln_b     = (const float*)d_in[6];
  const float* W_feat   = (const float*)d_in[7];
  const float* b_feat   = (const float*)d_in[8];
  const float* W_inproj = (const float*)d_in[9];
  const float* b_inproj = (const float*)d_in[10];
  const float* conv_w   = (const float*)d_in[11];
  const float* conv_b   = (const float*)d_in[12];
  const float* W_xproj  = (const float*)d_in[13];
  const float* W_dt     = (const float*)d_in[14];
  const float* b_dt     = (const float*)d_in[15];
  const float* D_param  = (const float*)d_in[16];
  const float* W_out    = (const float*)d_in[17];
  const float* b_out    = (const float*)d_in[18];
  const float* W_tr     = (const float*)d_in[19];
  const float* b_tr     = (const float*)d_in[20];
  const float* W_se     = (const float*)d_in[21];
  const float* b_se     = (const float*)d_in[22];
  const float* W_fin    = (const float*)d_in[23];
  const float* b_fin    = (const float*)d_in[24];

  hipLaunchKernelGGL(k_all, dim3(256), dim3(1024), 0, stream,
                     tc, cc, initv, W_cf, b_cf, ln_g, ln_b, W_feat, b_feat,
                     W_inproj, b_inproj, conv_w, conv_b, W_xproj, W_dt, b_dt,
                     D_param, W_out, b_out, W_tr, b_tr, W_se, b_se, W_fin, b_fin,
                     (float*)d_out);
}

// Round 6
// 2242.764 us; speedup vs baseline: 6.4131x; 2.1568x over previous
//
#include <hip/hip_runtime.h>
#include <hip/hip_bf16.h>

// Persistent fused decoder: 256 blocks x 1024 threads, 4 batch rows/block,
// 64 sequential steps, fp32 throughout.
// Key algebra:
//  - rank-7 feedback fold: inproj per step = xz_base + comb @ Wcx (7x2048)
//  - output fold: m=y@W_out only feeds trend/seas/comb LINEARLY ->
//      Wts = W_out @ [W_tr|W_se]  (1024x14),  bts = b_out@[W_tr|W_se]+[b_tr|b_se]
//    kills the 1024x512 GEMV (70% of step FLOPs) and its 2MB/step L2 traffic.

struct Pro {                       // prologue-only arrays (dead before scan)
  float x2[4][1024];               // [tc|cc]                16K
  float hb[4][512];                // h -> fused (in place)   8K
  float hin[4][512];               //                         8K
  float wf7[7][512];               // W_feat rows 512..518   14K
  float hpart[2][4][512];          // K-split partials       16K
  float wtrse[512][14];            // [W_tr | W_se] staged   28K
};
struct Sc {                        // scan-phase arrays
  float xc[4][1024];               // x_c, later y (in place) 16K
  float part2[4][4][160];          // P2 K-split partials    10K
  float proj[4][160];              // dt_r reduced (only :32 used) 2.5K
  float combs[4][8];
  float bcv[4];
  float ts[4][16];
  float bts[16];
};
union SMem { Pro pro; Sc sc; };

__global__ __launch_bounds__(1024) void k_all(
    const float* __restrict__ tc, const float* __restrict__ cc,
    const float* __restrict__ initv,
    const float* __restrict__ W_cf, const float* __restrict__ b_cf,
    const float* __restrict__ ln_g, const float* __restrict__ ln_b,
    const float* __restrict__ W_feat, const float* __restrict__ b_feat,
    const float* __restrict__ W_inproj, const float* __restrict__ b_inproj,
    const float* __restrict__ conv_w, const float* __restrict__ conv_b,
    const float* __restrict__ Wxp,
    const float* __restrict__ Wdt, const float* __restrict__ b_dt,
    const float* __restrict__ D_param,
    const float* __restrict__ Wout, const float* __restrict__ b_out,
    const float* __restrict__ Wtr, const float* __restrict__ b_tr,
    const float* __restrict__ Wse, const float* __restrict__ b_se,
    const float* __restrict__ W_fin, const float* __restrict__ b_fin,
    float* __restrict__ out) {
  __shared__ SMem S;
  __shared__ float WtsT[14][1024];   // persistent 56K: Wts transposed
  const int t = threadIdx.x;         // 0..1023
  const int r0 = blockIdx.x * 4;
  const int o9 = t & 511;
  const int kc9 = t >> 9;

  // ================= prologue =================
  for (int idx = t; idx < 4096; idx += 1024) {
    int r = idx >> 10, k = idx & 1023;
    S.pro.x2[r][k] = (k < 512) ? tc[(size_t)(r0 + r) * 512 + k]
                               : cc[(size_t)(r0 + r) * 512 + (k - 512)];
  }
  for (int idx = t; idx < 3584; idx += 1024) {
    int i = idx >> 9, k = idx & 511;
    S.pro.wf7[i][k] = W_feat[(size_t)(512 + i) * 512 + k];
  }
  for (int idx = t; idx < 7168; idx += 1024) {
    int o = idx / 14, c = idx - o * 14;
    S.pro.wtrse[o][c] = (c < 7) ? Wtr[o * 7 + c] : Wse[o * 7 + (c - 7)];
  }
  __syncthreads();

  // h = relu([tc,cc] @ W_cf + b_cf), K=1024 split in 2
  {
    float a0 = 0, a1 = 0, a2 = 0, a3 = 0;
    int k0 = kc9 * 512;
    for (int k = k0; k < k0 + 512; ++k) {
      float w = W_cf[(size_t)k * 512 + o9];
      a0 += S.pro.x2[0][k] * w; a1 += S.pro.x2[1][k] * w;
      a2 += S.pro.x2[2][k] * w; a3 += S.pro.x2[3][k] * w;
    }
    S.pro.hpart[kc9][0][o9] = a0; S.pro.hpart[kc9][1][o9] = a1;
    S.pro.hpart[kc9][2][o9] = a2; S.pro.hpart[kc9][3][o9] = a3;
  }
  __syncthreads();
  {
    float b = b_cf[o9];
#pragma unroll
    for (int rr = 0; rr < 2; ++rr) {
      int r = kc9 * 2 + rr;
      S.pro.hb[r][o9] = fmaxf(S.pro.hpart[0][r][o9] + S.pro.hpart[1][r][o9] + b, 0.f);
    }
  }
  __syncthreads();
  // LayerNorm -> fused (in place)
  if (t < 256) {
    int w = t >> 6, lane = t & 63;
    float s = 0.f, s2 = 0.f;
    for (int j = lane; j < 512; j += 64) { float v = S.pro.hb[w][j]; s += v; s2 += v * v; }
#pragma unroll
    for (int off = 32; off; off >>= 1) { s += __shfl_xor(s, off); s2 += __shfl_xor(s2, off); }
    float mu = s * (1.f / 512.f);
    float var = s2 * (1.f / 512.f) - mu * mu;
    float inv = rsqrtf(var + 1e-5f);
    for (int j = lane; j < 512; j += 64)
      S.pro.hb[w][j] = (S.pro.hb[w][j] - mu) * inv * ln_g[j] + ln_b[j];
  }
  __syncthreads();
  // hin = fused @ W_feat[:512] + b_feat, K=512 split in 2
  {
    float a0 = 0, a1 = 0, a2 = 0, a3 = 0;
    int k0 = kc9 * 256;
    for (int k = k0; k < k0 + 256; ++k) {
      float w = W_feat[(size_t)k * 512 + o9];
      a0 += S.pro.hb[0][k] * w; a1 += S.pro.hb[1][k] * w;
      a2 += S.pro.hb[2][k] * w; a3 += S.pro.hb[3][k] * w;
    }
    S.pro.hpart[kc9][0][o9] = a0; S.pro.hpart[kc9][1][o9] = a1;
    S.pro.hpart[kc9][2][o9] = a2; S.pro.hpart[kc9][3][o9] = a3;
  }
  __syncthreads();
  {
    float b = b_feat[o9];
#pragma unroll
    for (int rr = 0; rr < 2; ++rr) {
      int r = kc9 * 2 + rr;
      S.pro.hin[r][o9] = S.pro.hpart[0][r][o9] + S.pro.hpart[1][r][o9] + b;
    }
  }
  __syncthreads();

  // xz_base + rank-7 fold Wcx, into registers. Thread t: x-col t, z-col 1024+t.
  float xzbx[4], xzbz[4], wcxx[7], wcxz[7];
#pragma unroll
  for (int half = 0; half < 2; ++half) {
    int col = t + half * 1024;
    float a0 = 0, a1 = 0, a2 = 0, a3 = 0;
    float w0 = 0, w1 = 0, w2 = 0, w3 = 0, w4 = 0, w5 = 0, w6 = 0;
    for (int k = 0; k < 512; ++k) {
      float wi = W_inproj[(size_t)k * 2048 + col];
      a0 += S.pro.hin[0][k] * wi; a1 += S.pro.hin[1][k] * wi;
      a2 += S.pro.hin[2][k] * wi; a3 += S.pro.hin[3][k] * wi;
      w0 += S.pro.wf7[0][k] * wi; w1 += S.pro.wf7[1][k] * wi;
      w2 += S.pro.wf7[2][k] * wi; w3 += S.pro.wf7[3][k] * wi;
      w4 += S.pro.wf7[4][k] * wi; w5 += S.pro.wf7[5][k] * wi;
      w6 += S.pro.wf7[6][k] * wi;
    }
    float bi = b_inproj[col];
    if (half == 0) {
      xzbx[0] = a0 + bi; xzbx[1] = a1 + bi; xzbx[2] = a2 + bi; xzbx[3] = a3 + bi;
      wcxx[0] = w0; wcxx[1] = w1; wcxx[2] = w2; wcxx[3] = w3; wcxx[4] = w4;
      wcxx[5] = w5; wcxx[6] = w6;
    } else {
      xzbz[0] = a0 + bi; xzbz[1] = a1 + bi; xzbz[2] = a2 + bi; xzbz[3] = a3 + bi;
      wcxz[0] = w0; wcxz[1] = w1; wcxz[2] = w2; wcxz[3] = w3; wcxz[4] = w4;
      wcxz[5] = w5; wcxz[6] = w6;
    }
  }

  // Wts build: thread t owns k=t. WtsT[c][k] = sum_o Wout[k][o] * wtrse[o][c]
  {
    float acc[14];
#pragma unroll
    for (int c = 0; c < 14; ++c) acc[c] = 0.f;
    const float4* wo4 = reinterpret_cast<const float4*>(&Wout[(size_t)t * 512]);
#pragma unroll 2
    for (int o4 = 0; o4 < 128; ++o4) {
      float4 wv = wo4[o4];
#pragma unroll
      for (int j = 0; j < 4; ++j) {
        float w = (j == 0) ? wv.x : (j == 1) ? wv.y : (j == 2) ? wv.z : wv.w;
        int o = o4 * 4 + j;
#pragma unroll
        for (int c = 0; c < 14; ++c) acc[c] += w * S.pro.wtrse[o][c];
      }
    }
#pragma unroll
    for (int c = 0; c < 14; ++c) WtsT[c][t] = acc[c];
  }
  __syncthreads();

  // bts[c] = b_out @ wtrse[:,c] + (b_tr|b_se)[c]   (reads wtrse: still intact)
  if (t < 14) {
    float s = (t < 7) ? b_tr[t] : b_se[t - 7];
    for (int o = 0; o < 512; ++o) s += b_out[o] * S.pro.wtrse[o][t];
    S.sc.bts[t] = s;   // writes land in dead Pro region (offset ~29K)
  }
  if (t < 28) S.sc.combs[t / 7][t % 7] = initv[(r0 + t / 7) * 7 + (t % 7)];

  // step-invariant per-thread constants (j = t)
  const float cw3  = conv_w[t * 4 + 3];
  const float cbv  = conv_b[t];
  const float dpar = D_param[t];
  const float bdtv = b_dt[t];
  __syncthreads();

  // ================= 64 sequential decode steps =================
  float zsr[4], xcr[4];
  for (int step = 0; step < 64; ++step) {
    // P1: xz = xz_base + comb @ Wcx; x_c = silu(conv) -> LDS+reg; silu(z) -> reg
#pragma unroll
    for (int r = 0; r < 4; ++r) {
      float v = xzbx[r], u = xzbz[r];
#pragma unroll
      for (int i = 0; i < 7; ++i) {
        float cb_ = S.sc.combs[r][i];
        v += cb_ * wcxx[i];
        u += cb_ * wcxz[i];
      }
      v = v * cw3 + cbv;
      float sv = v / (1.f + expf(-v));
      xcr[r] = sv;
      S.sc.xc[r][t] = sv;
      zsr[r] = u / (1.f + expf(-u));
    }
    __syncthreads();

    // P2: part2 = x_c @ W_xproj, K=1024 split in 4 quarters (640 threads)
    if (t < 640) {
      int kc = t / 160, p = t - kc * 160;
      const float2* x0 = reinterpret_cast<const float2*>(&S.sc.xc[0][0]);
      const float2* x1 = reinterpret_cast<const float2*>(&S.sc.xc[1][0]);
      const float2* x2_ = reinterpret_cast<const float2*>(&S.sc.xc[2][0]);
      const float2* x3 = reinterpret_cast<const float2*>(&S.sc.xc[3][0]);
      float a0 = 0, a1 = 0, a2 = 0, a3 = 0;
      int k20 = kc * 128;
#pragma unroll 4
      for (int k2 = k20; k2 < k20 + 128; ++k2) {
        float w0 = Wxp[(size_t)(2 * k2) * 160 + p];
        float w1 = Wxp[(size_t)(2 * k2 + 1) * 160 + p];
        float2 v0 = x0[k2], v1 = x1[k2], v2 = x2_[k2], v3 = x3[k2];
        a0 += v0.x * w0 + v0.y * w1;
        a1 += v1.x * w0 + v1.y * w1;
        a2 += v2.x * w0 + v2.y * w1;
        a3 += v3.x * w0 + v3.y * w1;
      }
      S.sc.part2[kc][0][p] = a0; S.sc.part2[kc][1][p] = a1;
      S.sc.part2[kc][2][p] = a2; S.sc.part2[kc][3][p] = a3;
    }
    __syncthreads();

    // reduce dt_r (proj[:, :32]) + bc = <Bm,Cm> in parallel thread ranges
    if (t < 128) {
      int r = t >> 5, p = t & 31;
      S.sc.proj[r][p] = S.sc.part2[0][r][p] + S.sc.part2[1][r][p] +
                        S.sc.part2[2][r][p] + S.sc.part2[3][r][p];
    } else if (t >= 256 && t < 512) {
      int r = (t - 256) >> 6, n = t & 63;
      float bm = S.sc.part2[0][r][32 + n] + S.sc.part2[1][r][32 + n] +
                 S.sc.part2[2][r][32 + n] + S.sc.part2[3][r][32 + n];
      float cm = S.sc.part2[0][r][96 + n] + S.sc.part2[1][r][96 + n] +
                 S.sc.part2[2][r][96 + n] + S.sc.part2[3][r][96 + n];
      float pr = bm * cm;
#pragma unroll
      for (int off = 32; off; off >>= 1) pr += __shfl_xor(pr, off);
      if (n == 0) S.sc.bcv[r] = pr;
    }
    __syncthreads();

    // P3: dt = softplus(dt_r @ W_dt + b_dt); y = (dt*bc + D)*x_c*silu(z) -> xc
    {
      float a0 = bdtv, a1 = bdtv, a2 = bdtv, a3 = bdtv;
#pragma unroll
      for (int q2 = 0; q2 < 16; ++q2) {
        float w0 = Wdt[(size_t)(2 * q2) * 1024 + t];
        float w1 = Wdt[(size_t)(2 * q2 + 1) * 1024 + t];
        float2 p0 = reinterpret_cast<const float2*>(&S.sc.proj[0][0])[q2];
        float2 p1 = reinterpret_cast<const float2*>(&S.sc.proj[1][0])[q2];
        float2 p2 = reinterpret_cast<const float2*>(&S.sc.proj[2][0])[q2];
        float2 p3 = reinterpret_cast<const float2*>(&S.sc.proj[3][0])[q2];
        a0 += p0.x * w0 + p0.y * w1;
        a1 += p1.x * w0 + p1.y * w1;
        a2 += p2.x * w0 + p2.y * w1;
        a3 += p3.x * w0 + p3.y * w1;
      }
      float accs[4] = {a0, a1, a2, a3};
#pragma unroll
      for (int r = 0; r < 4; ++r) {
        float v = accs[r];
        float sp = fmaxf(v, 0.f) + log1pf(expf(-fabsf(v)));
        S.sc.xc[r][t] = (sp * S.sc.bcv[r] + dpar) * xcr[r] * zsr[r];
      }
    }
    __syncthreads();

    // Pts: ts = y @ Wts + bts. Wave w (0..13) owns output c=w, lanes split K.
    {
      int w = t >> 6, l = t & 63;
      if (w < 14) {
        float a0 = 0, a1 = 0, a2 = 0, a3 = 0;
#pragma unroll 4
        for (int i = 0; i < 16; ++i) {
          int k = l + i * 64;
          float wt = WtsT[w][k];
          a0 += S.sc.xc[0][k] * wt; a1 += S.sc.xc[1][k] * wt;
          a2 += S.sc.xc[2][k] * wt; a3 += S.sc.xc[3][k] * wt;
        }
#pragma unroll
        for (int off = 32; off; off >>= 1) {
          a0 += __shfl_xor(a0, off); a1 += __shfl_xor(a1, off);
          a2 += __shfl_xor(a2, off); a3 += __shfl_xor(a3, off);
        }
        if (l == 0) {
          float b = S.sc.bts[w];
          float v0 = a0 + b, v1 = a1 + b, v2 = a2 + b, v3 = a3 + b;
          S.sc.ts[0][w] = v0; S.sc.ts[1][w] = v1;
          S.sc.ts[2][w] = v2; S.sc.ts[3][w] = v3;
          float vals[4] = {v0, v1, v2, v3};
#pragma unroll
          for (int r = 0; r < 4; ++r) {
            size_t idx = ((size_t)(r0 + r) * 64 + step) * 7;
            if (w < 7) out[idx + w] = vals[r];
            else out[458752 + idx + (w - 7)] = vals[r];
          }
        }
      }
    }
    __syncthreads();

    // P7: comb = [trend,seas] @ W_fin + b_fin, write out + feedback
    if (t < 28) {
      int r = t / 7, c = t - (t / 7) * 7;
      float s = b_fin[c];
#pragma unroll
      for (int i = 0; i < 14; ++i) s += S.sc.ts[r][i] * W_fin[i * 7 + c];
      S.sc.combs[r][c] = s;
      out[917504 + ((size_t)(r0 + r) * 64 + step) * 7 + c] = s;
    }
    __syncthreads();
  }
}

extern "C" void kernel_launch(void* const* d_in, const int* in_sizes, int n_in,
                              void* d_out, int out_size, void* d_ws, size_t ws_size,
                              hipStream_t stream) {
  const float* tc       = (const float*)d_in[0];
  const float* cc       = (const float*)d_in[1];
  const float* initv    = (const float*)d_in[2];
  const float* W_cf     = (const float*)d_in[3];
  const float* b_cf     = (const float*)d_in[4];
  const float* ln_g     = (const float*)d_in[5];
  const float* ln_b     = (const float*)d_in[6];
  const float* W_feat   = (const float*)d_in[7];
  const float* b_feat   = (const float*)d_in[8];
  const float* W_inproj = (const float*)d_in[9];
  const float* b_inproj = (const float*)d_in[10];
  const float* conv_w   = (const float*)d_in[11];
  const float* conv_b   = (const float*)d_in[12];
  const float* W_xproj  = (const float*)d_in[13];
  const float* W_dt     = (const float*)d_in[14];
  const float* b_dt     = (const float*)d_in[15];
  const float* D_param  = (const float*)d_in[16];
  const float* W_out    = (const float*)d_in[17];
  const float* b_out    = (const float*)d_in[18];
  const float* W_tr     = (const float*)d_in[19];
  const float* b_tr     = (const float*)d_in[20];
  const float* W_se     = (const float*)d_in[21];
  const float* b_se     = (const float*)d_in[22];
  const float* W_fin    = (const float*)d_in[23];
  const float* b_fin    = (const float*)d_in[24];

  hipLaunchKernelGGL(k_all, dim3(256), dim3(1024), 0, stream,
                     tc, cc, initv, W_cf, b_cf, ln_g, ln_b, W_feat, b_feat,
                     W_inproj, b_inproj, conv_w, conv_b, W_xproj, W_dt, b_dt,
                     D_param, W_out, b_out, W_tr, b_tr, W_se, b_se, W_fin, b_fin,
                     (float*)d_out);
}